// Round 6
// baseline (204.841 us; speedup 1.0000x reference)
//
#include <hip/hip_runtime.h>

// SynthesisStage: modulated conv2d w/ adaptive kernel selection.
// B=8, Ci=Co=256, H=W=128, K=3, N=4.
// v6: register fragment prefetch pipeline. 1 barrier per K-tile; B-fragments
// for tile t+1 are ds_read during tile t's MFMA; A staged via global_load_lds
// 2 tiles ahead (tri-buffer, counted vmcnt, never drain-0 in loop).
// Uniform 72 tiles/block (border rows zero-filled in XR pack).

typedef __attribute__((ext_vector_type(4))) float f32x4;
typedef __attribute__((ext_vector_type(8))) short s16x8;

#define NB   8
#define NCI  256
#define NCO  256
#define NHW  128
#define NKER 4

#define SB0 __builtin_amdgcn_sched_barrier(0)
#define BAR __builtin_amdgcn_s_barrier()
#define WAITV(N) asm volatile("s_waitcnt vmcnt(" #N ")" ::: "memory")
#define WAITL0   asm volatile("s_waitcnt lgkmcnt(0)" ::: "memory")

__device__ __forceinline__ unsigned short f2bf(float f) {
  unsigned int u = __builtin_bit_cast(unsigned int, f);
  u += 0x7FFFu + ((u >> 16) & 1u);          // round-to-nearest-even
  return (unsigned short)(u >> 16);
}

__device__ __forceinline__ void gl_lds16(const void* g, void* l) {
  __builtin_amdgcn_global_load_lds(
      (const __attribute__((address_space(1))) void*)(unsigned long long)(uintptr_t)g,
      (__attribute__((address_space(3))) void*)(unsigned int)(uintptr_t)l,
      16, 0, 0);
}

// ---------------------------------------------------------------------------
// Kernel 1: modulated+demodulated weights -> bf16 pre-swizzled 16KB tiles.
// Tile T = (b*9+tap)*8 + kb holds 256co x 32ci as 128 rows x 128B:
// (co,ci5) at row=co>>1, byte=((((co&1)*4+(ci5>>3)) ^ (row&7))<<4)+(ci5&7)*2
// ---------------------------------------------------------------------------
__global__ __launch_bounds__(256) void prep_k(
    const float* __restrict__ weight,    // [N][Co][Ci][3][3]
    const float* __restrict__ styles,    // [B][Ci]
    const float* __restrict__ selector,  // [B][N]
    unsigned short* __restrict__ wmod)   // tiled-swizzled, 9.44 MB
{
  int bid = blockIdx.x;
  int b = bid >> 8, co = bid & 255;
  int ci = threadIdx.x;

  float sel[NKER];
#pragma unroll
  for (int n = 0; n < NKER; ++n) sel[n] = selector[b * NKER + n];

  float a[9];
#pragma unroll
  for (int j = 0; j < 9; ++j) a[j] = 0.f;
#pragma unroll
  for (int n = 0; n < NKER; ++n) {
    const float* wp = weight + (size_t)((n * NCO + co) * NCI + ci) * 9;
    float s = sel[n];
#pragma unroll
    for (int j = 0; j < 9; ++j) a[j] += s * wp[j];
  }
  float st = styles[b * NCI + ci];
  float ss = 0.f;
#pragma unroll
  for (int j = 0; j < 9; ++j) { a[j] *= st; ss += a[j] * a[j]; }

  for (int off = 32; off; off >>= 1) ss += __shfl_down(ss, off, 64);
  __shared__ float red[4];
  int wid = threadIdx.x >> 6, lane = threadIdx.x & 63;
  if (lane == 0) red[wid] = ss;
  __syncthreads();
  float tot = red[0] + red[1] + red[2] + red[3];
  float d = rsqrtf(tot + 1e-8f);

  int kb = ci >> 5, ci5 = ci & 31;
  int row = co >> 1;
  int slot = (((co & 1) << 2) + (ci5 >> 3)) ^ (row & 7);
  int boff = (slot << 4) + ((ci5 & 7) << 1);     // byte in 128B row
#pragma unroll
  for (int j = 0; j < 9; ++j) {
    size_t T = (size_t)((b * 9 + j) * 8 + kb);
    wmod[(T << 13) + (row << 6) + (boff >> 1)] = f2bf(a[j] * d);
  }
}

// ---------------------------------------------------------------------------
// Kernel 2: implicit-GEMM conv, frag-prefetch pipeline.
// block = (b, h); 256 thr = 4 waves, wave tile 64co x 128px.
// ---------------------------------------------------------------------------
__global__ __launch_bounds__(256, 2) void conv_k(
    const float* __restrict__ x,              // [B][Ci][H][W] f32
    const unsigned short* __restrict__ wg,    // pre-swizzled wmod tiles
    const float* __restrict__ noise,          // [B][Co][H][W]
    float* __restrict__ out)                  // [B][Co][H][W]
{
  extern __shared__ __align__(16) char smem[];
  char* AlB = smem;                  // 3 x 16KB A tri-buffer
  char* XRs = smem + 3 * 16384;      // 2 x 8KB XR dbuf

  int orig = blockIdx.x;             // 1024 blocks
  int b = orig & 7;                  // XCD-resident sample
  int h = orig >> 3;

  int t = threadIdx.x;
  int lane = t & 63;
  int wid = t >> 6;
  int cow = wid << 6;
  int ll = lane & 15;
  int ks = lane >> 4;                // k-slice 0..3

  f32x4 acc[4][8];
#pragma unroll
  for (int m = 0; m < 4; ++m)
#pragma unroll
    for (int n = 0; n < 8; ++n) acc[m][n] = (f32x4){0.f, 0.f, 0.f, 0.f};

  // x staging: thread owns ci-pair (c,c+1) x 8 w's (w = wi + 16*j2)
  int c = ((t >> 4) & 15) * 2;
  int wi = t & 15;
  float xlo[8], xhi[8];
  unsigned xmask = 0xFFFFFFFFu;

  auto issueX = [&](int g) {
    int gc = g < 24 ? g : 23;
    int dh = gc >> 3, kb = gc & 7;
    int hy = h + dh - 1;
    xmask = ((unsigned)hy < 128u) ? 0xFFFFFFFFu : 0u;
    int hyc = hy < 0 ? 0 : (hy > 127 ? 127 : hy);
    const float* base = x + ((size_t)(b * NCI + kb * 32 + c) * NHW + hyc) * NHW + wi;
#pragma unroll
    for (int j2 = 0; j2 < 8; ++j2) {
      xlo[j2] = base[j2 * 16];
      xhi[j2] = base[NHW * NHW + j2 * 16];
    }
  };

  auto issueA = [&](int tc, char* dst) {     // stage tile tc (clamped)
    if (tc > 71) tc = 71;
    int g = tc / 3, tap = tc - g * 3;
    int dh = g >> 3, kb = g & 7;
    const char* src = (const char*)wg +
        ((size_t)((b * 9 + dh * 3 + tap) * 8 + kb) << 14);
#pragma unroll
    for (int i = 0; i < 4; ++i) {
      int ch = wid * 4 + i;
      gl_lds16(src + ch * 1024 + lane * 16, dst + ch * 1024 + lane * 16);
    }
  };

  auto packXR = [&](int g) {
    char* dstb = XRs + (g & 1) * 8192;
    int slot = (((wi & 1) << 2) + (c >> 3)) ^ ((wi >> 1) & 7);
    char* p0 = dstb + (wi >> 1) * 128 + (slot << 4) + ((c & 7) << 1);
#pragma unroll
    for (int j2 = 0; j2 < 8; ++j2) {
      unsigned pk = ((unsigned)f2bf(xhi[j2]) << 16) | f2bf(xlo[j2]);
      *(unsigned*)(p0 + j2 * 1024) = pk & xmask;  // zero-fill border rows
    }
  };

  auto readAF = [&](const char* Ab, s16x8* af) {
#pragma unroll
    for (int m = 0; m < 4; ++m) {
      int co = cow + m * 16 + ll;
      int row = co >> 1;
      int slot = (((co & 1) << 2) + ks) ^ (row & 7);
      af[m] = *(const s16x8*)(Ab + row * 128 + (slot << 4));
    }
  };

// prefetch B-fragments (DW is a literal: edge branch folds at compile time)
#define PFB(XRBASE, DW, bf)                                              \
  {                                                                      \
    const char* Xb = (XRBASE);                                           \
    _Pragma("unroll")                                                    \
    for (int n = 0; n < 8; ++n) {                                        \
      int wn = n * 16 + ll + (DW) - 1;                                   \
      if (((DW) == 0 && n == 0) || ((DW) == 2 && n == 7)) {              \
        int wx = wn < 0 ? 0 : (wn > 127 ? 127 : wn);                     \
        int row = wx >> 1;                                               \
        int slot = (((wx & 1) << 2) + ks) ^ (row & 7);                   \
        s16x8 bv = *(const s16x8*)(Xb + row * 128 + (slot << 4));        \
        if (wn != wx) { s16x8 z = {0, 0, 0, 0, 0, 0, 0, 0}; bv = z; }    \
        bf[n] = bv;                                                      \
      } else {                                                           \
        int row = wn >> 1;                                               \
        int slot = (((wn & 1) << 2) + ks) ^ (row & 7);                   \
        bf[n] = *(const s16x8*)(Xb + row * 128 + (slot << 4));           \
      }                                                                  \
    }                                                                    \
  }

#define MFMA32(af, bf)                                                   \
  __builtin_amdgcn_s_setprio(1);                                         \
  _Pragma("unroll")                                                      \
  for (int m = 0; m < 4; ++m)                                            \
    _Pragma("unroll")                                                    \
    for (int n = 0; n < 8; ++n)                                          \
      acc[m][n] = __builtin_amdgcn_mfma_f32_16x16x32_bf16(               \
          af[m], bf[n], acc[m][n], 0, 0, 0);                             \
  __builtin_amdgcn_s_setprio(0);

  s16x8 bfA[8], bfB[8], af[4];

  // ---- prologue: x(0)[16], A(0)->buf0, A(1)->buf1; pack XR(0) ----
  issueX(0); SB0;
  issueA(0, AlB); SB0;
  issueA(1, AlB + 16384); SB0;
  WAITV(8); SB0;                     // drain x16; keep A0,A1
  packXR(0);
  WAITV(4); SB0;                     // drain A0; keep A1
  WAITL0; SB0;
  BAR; SB0;
  PFB(XRs, 0, bfA);                  // frags for tile 0 (tap0)

  // ---- main loop: 12 x 6 tiles; waits per simulated per-wave ledger ----
#pragma unroll 1
  for (int gg = 0; gg < 12; ++gg) {
    int t0 = gg * 6;
    int g0 = gg * 2;
    // T0 (tap0, reads buf0)
    WAITV(4); SB0; BAR; SB0;
    issueA(t0 + 2, AlB + 2 * 16384); SB0;
    issueX(g0 + 1); SB0;
    readAF(AlB, af);
    PFB(XRs, 1, bfB);
    MFMA32(af, bfA);
    // T1 (tap1, buf1)
    WAITV(20); SB0; BAR; SB0;
    issueA(t0 + 3, AlB); SB0;
    WAITV(4); SB0;                   // drain x16 (+A(t0+2)); keep A(t0+3)
    packXR(g0 + 1);
    readAF(AlB + 16384, af);
    PFB(XRs, 2, bfA);
    MFMA32(af, bfB);
    // T2 (tap2, buf2)
    WAITL0; SB0;                     // pack writes drained before barrier
    WAITV(4); SB0; BAR; SB0;
    issueA(t0 + 4, AlB + 16384); SB0;
    readAF(AlB + 2 * 16384, af);
    PFB(XRs + 8192, 0, bfB);
    MFMA32(af, bfA);
    // T3 (tap0, buf0)
    WAITV(4); SB0; BAR; SB0;
    issueA(t0 + 5, AlB + 2 * 16384); SB0;
    issueX(g0 + 2); SB0;
    readAF(AlB, af);
    PFB(XRs + 8192, 1, bfA);
    MFMA32(af, bfB);
    // T4 (tap1, buf1)
    WAITV(20); SB0; BAR; SB0;
    issueA(t0 + 6, AlB); SB0;
    WAITV(4); SB0;
    packXR(g0 + 2);
    readAF(AlB + 16384, af);
    PFB(XRs + 8192, 2, bfB);
    MFMA32(af, bfA);
    // T5 (tap2, buf2)
    WAITL0; SB0;
    WAITV(4); SB0; BAR; SB0;
    issueA(t0 + 7, AlB + 16384); SB0;
    readAF(AlB + 2 * 16384, af);
    PFB(XRs, 0, bfA);
    MFMA32(af, bfB);
  }

  // epilogue: D[row=ks*4+j][col=ll], fused noise add
  int pr4 = ks * 4;
#pragma unroll
  for (int m = 0; m < 4; ++m) {
#pragma unroll
    for (int n = 0; n < 8; ++n) {
      int px = n * 16 + ll;
#pragma unroll
      for (int j = 0; j < 4; ++j) {
        int co = cow + m * 16 + pr4 + j;
        size_t idx = ((size_t)(b * NCO + co) * NHW + h) * NHW + px;
        out[idx] = acc[m][n][j] + noise[idx];
      }
    }
  }
}

// ---------------------------------------------------------------------------
extern "C" void kernel_launch(void* const* d_in, const int* in_sizes, int n_in,
                              void* d_out, int out_size, void* d_ws, size_t ws_size,
                              hipStream_t stream) {
  const float* x        = (const float*)d_in[0];
  const float* weight   = (const float*)d_in[1];
  const float* styles   = (const float*)d_in[2];
  const float* selector = (const float*)d_in[3];
  const float* noise    = (const float*)d_in[4];
  float* out = (float*)d_out;

  // workspace: ONLY wmod (pre-swizzled tiles) = 9,437,184 bytes
  unsigned short* wmod = (unsigned short*)d_ws;

  hipLaunchKernelGGL(prep_k, dim3(NB * NCO), dim3(256), 0, stream,
                     weight, styles, selector, wmod);
  hipLaunchKernelGGL(conv_k, dim3(NB * NHW), dim3(256), 64 * 1024, stream,
                     x, wmod, noise, out);
}

// Round 7
// 174.030 us; speedup vs baseline: 1.1770x; 1.1770x over previous
//
#include <hip/hip_runtime.h>

// SynthesisStage: modulated conv2d w/ adaptive kernel selection.
// B=8, Ci=Co=256, H=W=128, K=3, N=4.
// v7: A-fragments loaded DIRECTLY global->VGPR from fragment-ordered wmod
// (no A LDS traffic, no A barriers). LDS holds only the x-row dbuf (16KB).
// One raw s_barrier per (dh,kb) group (24/block); global loads cross
// barriers; compiler emits exact counted vmcnt. af reg-double-buffered.

typedef __attribute__((ext_vector_type(4))) float f32x4;
typedef __attribute__((ext_vector_type(8))) short s16x8;

#define NB   8
#define NCI  256
#define NCO  256
#define NHW  128
#define NKER 4

#define SB0 __builtin_amdgcn_sched_barrier(0)
#define BAR __builtin_amdgcn_s_barrier()
#define WAITL0 asm volatile("s_waitcnt lgkmcnt(0)" ::: "memory")

__device__ __forceinline__ unsigned short f2bf(float f) {
  unsigned int u = __builtin_bit_cast(unsigned int, f);
  u += 0x7FFFu + ((u >> 16) & 1u);          // round-to-nearest-even
  return (unsigned short)(u >> 16);
}

// ---------------------------------------------------------------------------
// Kernel 1: modulated+demodulated weights -> bf16 in FRAGMENT-DIRECT order.
// Tile T=(b*9+tap)*8+kb is 16KB: [chunk co>>4][lane (ci5>>3)*16+(co&15)][8 ci]
// so conv_k wave wid reads af[m] as one coalesced dwordx4 at
// T*16384 + wid*4096 + m*1024 + lane*16.
// ---------------------------------------------------------------------------
__global__ __launch_bounds__(256) void prep_k(
    const float* __restrict__ weight,    // [N][Co][Ci][3][3]
    const float* __restrict__ styles,    // [B][Ci]
    const float* __restrict__ selector,  // [B][N]
    unsigned short* __restrict__ wmod)   // fragment-ordered, 9.44 MB
{
  int bid = blockIdx.x;
  int b = bid >> 8, co = bid & 255;
  int ci = threadIdx.x;

  float sel[NKER];
#pragma unroll
  for (int n = 0; n < NKER; ++n) sel[n] = selector[b * NKER + n];

  float a[9];
#pragma unroll
  for (int j = 0; j < 9; ++j) a[j] = 0.f;
#pragma unroll
  for (int n = 0; n < NKER; ++n) {
    const float* wp = weight + (size_t)((n * NCO + co) * NCI + ci) * 9;
    float s = sel[n];
#pragma unroll
    for (int j = 0; j < 9; ++j) a[j] += s * wp[j];
  }
  float st = styles[b * NCI + ci];
  float ss = 0.f;
#pragma unroll
  for (int j = 0; j < 9; ++j) { a[j] *= st; ss += a[j] * a[j]; }

  for (int off = 32; off; off >>= 1) ss += __shfl_down(ss, off, 64);
  __shared__ float red[4];
  int wid = threadIdx.x >> 6, lane = threadIdx.x & 63;
  if (lane == 0) red[wid] = ss;
  __syncthreads();
  float tot = red[0] + red[1] + red[2] + red[3];
  float d = rsqrtf(tot + 1e-8f);

  // fragment-direct address (shorts): T*8192 + (co>>4)*512 +
  //   ((ci&31)>>3)*128 + (co&15)*8 + (ci&7)
  int kb = ci >> 5;
  size_t base = (size_t)(co >> 4) * 512 +
                (size_t)(((ci & 31) >> 3) * 128) + ((co & 15) * 8) + (ci & 7);
#pragma unroll
  for (int j = 0; j < 9; ++j) {
    size_t T = (size_t)((b * 9 + j) * 8 + kb);
    wmod[(T << 13) + base] = f2bf(a[j] * d);
  }
}

// ---------------------------------------------------------------------------
// Kernel 2: implicit-GEMM conv; A direct-from-global, B via 16KB LDS dbuf.
// block = (b, h); 256 thr = 4 waves, wave tile 64co x 128px; 72 K-tiles.
// ---------------------------------------------------------------------------
__global__ __launch_bounds__(256, 2) void conv_k(
    const float* __restrict__ x,              // [B][Ci][H][W] f32
    const unsigned short* __restrict__ wg,    // fragment-ordered wmod
    const float* __restrict__ noise,          // [B][Co][H][W]
    float* __restrict__ out)                  // [B][Co][H][W]
{
  extern __shared__ __align__(16) char XRs[]; // 2 x 8KB XR dbuf

  int orig = blockIdx.x;             // 1024 blocks
  int b = orig & 7;                  // XCD-resident sample
  int h = orig >> 3;

  int t = threadIdx.x;
  int lane = t & 63;
  int wid = t >> 6;
  int cow = wid << 6;
  int ll = lane & 15;
  int ks = lane >> 4;                // k-slice 0..3

  f32x4 acc[4][8];
#pragma unroll
  for (int m = 0; m < 4; ++m)
#pragma unroll
    for (int n = 0; n < 8; ++n) acc[m][n] = (f32x4){0.f, 0.f, 0.f, 0.f};

  // x staging: thread owns ci-pair (c,c+1) x 8 w's (w = wi + 16*j2)
  int c = ((t >> 4) & 15) * 2;
  int wi = t & 15;
  float xlo[8], xhi[8];
  unsigned xmask = 0xFFFFFFFFu;

  auto issueX = [&](int g) {
    int gc = g < 24 ? g : 23;
    int dh = gc >> 3, kb = gc & 7;
    int hy = h + dh - 1;
    xmask = ((unsigned)hy < 128u) ? 0xFFFFFFFFu : 0u;
    int hyc = hy < 0 ? 0 : (hy > 127 ? 127 : hy);
    const float* base = x + ((size_t)(b * NCI + kb * 32 + c) * NHW + hyc) * NHW + wi;
#pragma unroll
    for (int j2 = 0; j2 < 8; ++j2) {
      xlo[j2] = base[j2 * 16];
      xhi[j2] = base[NHW * NHW + j2 * 16];
    }
  };

  // A-fragments straight from global (fragment-ordered tile, coalesced)
  auto issueAF = [&](int tc, s16x8* af) {
    if (tc > 71) tc = 71;
    int g = tc / 3, tap = tc - g * 3;
    int dh = g >> 3, kb = g & 7;
    const char* src = (const char*)wg +
        ((size_t)((b * 9 + dh * 3 + tap) * 8 + kb) << 14) + wid * 4096 + lane * 16;
#pragma unroll
    for (int m = 0; m < 4; ++m)
      af[m] = *(const s16x8*)(src + m * 1024);
  };

  auto packXR = [&](int g) {
    char* dstb = XRs + (g & 1) * 8192;
    int slot = (((wi & 1) << 2) + (c >> 3)) ^ ((wi >> 1) & 7);
    char* p0 = dstb + (wi >> 1) * 128 + (slot << 4) + ((c & 7) << 1);
#pragma unroll
    for (int j2 = 0; j2 < 8; ++j2) {
      unsigned pk = ((unsigned)f2bf(xhi[j2]) << 16) | f2bf(xlo[j2]);
      *(unsigned*)(p0 + j2 * 1024) = pk & xmask;  // zero-fill border rows
    }
  };

// B-fragments (DW literal: edge branch folds at compile time)
#define PFB(XRBASE, DW, bf)                                              \
  {                                                                      \
    const char* Xb = (XRBASE);                                           \
    _Pragma("unroll")                                                    \
    for (int n = 0; n < 8; ++n) {                                        \
      int wn = n * 16 + ll + (DW) - 1;                                   \
      if (((DW) == 0 && n == 0) || ((DW) == 2 && n == 7)) {              \
        int wx = wn < 0 ? 0 : (wn > 127 ? 127 : wn);                     \
        int row = wx >> 1;                                               \
        int slot = (((wx & 1) << 2) + ks) ^ (row & 7);                   \
        s16x8 bv = *(const s16x8*)(Xb + row * 128 + (slot << 4));        \
        if (wn != wx) { s16x8 z = {0, 0, 0, 0, 0, 0, 0, 0}; bv = z; }    \
        bf[n] = bv;                                                      \
      } else {                                                           \
        int row = wn >> 1;                                               \
        int slot = (((wn & 1) << 2) + ks) ^ (row & 7);                   \
        bf[n] = *(const s16x8*)(Xb + row * 128 + (slot << 4));           \
      }                                                                  \
    }                                                                    \
  }

#define MFMA32(af, bf)                                                   \
  __builtin_amdgcn_s_setprio(1);                                         \
  _Pragma("unroll")                                                      \
  for (int m = 0; m < 4; ++m)                                            \
    _Pragma("unroll")                                                    \
    for (int n = 0; n < 8; ++n)                                          \
      acc[m][n] = __builtin_amdgcn_mfma_f32_16x16x32_bf16(               \
          af[m], bf[n], acc[m][n], 0, 0, 0);                             \
  __builtin_amdgcn_s_setprio(0);

  s16x8 afA[4], afB[4], bf[8];

  // ---- prologue: x(0), af(0)->A; pack XR(0) ----
  issueX(0); SB0;
  issueAF(0, afA); SB0;
  packXR(0);                          // compiler waits x via counted vmcnt

  // ---- main loop: 12 x 6 tiles (2 groups); 1 barrier per group ----
#pragma unroll 1
  for (int gg = 0; gg < 12; ++gg) {
    int g0 = gg * 2, t0 = gg * 6;
    // T0: group g0 (xr buf0), tap0, af=afA
    WAITL0; SB0; BAR; SB0;
    PFB(XRs, 0, bf);
    issueAF(t0 + 1, afB); SB0;
    issueX(g0 + 1); SB0;
    MFMA32(afA, bf);
    // T1: tap1, af=afB
    PFB(XRs, 1, bf);
    issueAF(t0 + 2, afA); SB0;
    MFMA32(afB, bf);
    // T2: tap2, af=afA
    PFB(XRs, 2, bf);
    issueAF(t0 + 3, afB); SB0;
    packXR(g0 + 1);
    MFMA32(afA, bf);
    // T3: group g0+1 (xr buf1), tap0, af=afB
    WAITL0; SB0; BAR; SB0;
    PFB(XRs + 8192, 0, bf);
    issueAF(t0 + 4, afA); SB0;
    issueX(g0 + 2); SB0;
    MFMA32(afB, bf);
    // T4: tap1, af=afA
    PFB(XRs + 8192, 1, bf);
    issueAF(t0 + 5, afB); SB0;
    MFMA32(afA, bf);
    // T5: tap2, af=afB
    PFB(XRs + 8192, 2, bf);
    issueAF(t0 + 6, afA); SB0;
    packXR(g0 + 2);
    MFMA32(afB, bf);
  }

  // epilogue: D[row=ks*4+j][col=ll], fused noise add
  int pr4 = ks * 4;
#pragma unroll
  for (int m = 0; m < 4; ++m) {
#pragma unroll
    for (int n = 0; n < 8; ++n) {
      int px = n * 16 + ll;
#pragma unroll
      for (int j = 0; j < 4; ++j) {
        int co = cow + m * 16 + pr4 + j;
        size_t idx = ((size_t)(b * NCO + co) * NHW + h) * NHW + px;
        out[idx] = acc[m][n][j] + noise[idx];
      }
    }
  }
}

// ---------------------------------------------------------------------------
extern "C" void kernel_launch(void* const* d_in, const int* in_sizes, int n_in,
                              void* d_out, int out_size, void* d_ws, size_t ws_size,
                              hipStream_t stream) {
  const float* x        = (const float*)d_in[0];
  const float* weight   = (const float*)d_in[1];
  const float* styles   = (const float*)d_in[2];
  const float* selector = (const float*)d_in[3];
  const float* noise    = (const float*)d_in[4];
  float* out = (float*)d_out;

  // workspace: ONLY wmod (fragment-ordered) = 9,437,184 bytes
  unsigned short* wmod = (unsigned short*)d_ws;

  hipLaunchKernelGGL(prep_k, dim3(NB * NCO), dim3(256), 0, stream,
                     weight, styles, selector, wmod);
  hipLaunchKernelGGL(conv_k, dim3(NB * NHW), dim3(256), 16 * 1024, stream,
                     x, wmod, noise, out);
}